// Round 9
// baseline (800.749 us; speedup 1.0000x reference)
//
#include <hip/hip_runtime.h>
#include <hip/hip_bf16.h>
#include <math.h>

#define H 128
#define RS 136    // LDS row stride in shorts (128 + 8 pad; keeps ds_read_b128 16B-aligned)
#define BSH 9     // bin shift: 512 nodes per bin
#define BINW 512
#define BCAP 11264  // max edges/bin for LDS sort
#define BSLOT 12288 // per-bin slot capacity in temp (direct scatter)
#define KEDGE 4096  // edges per partition block
#define EPT 16      // edges per thread (KEDGE/256)
#define MAXBINS 1024
#define IDXCAP 4352 // block idx-stage capacity in ints (= Alo bytes / 4)

typedef __attribute__((ext_vector_type(8))) short short8;
typedef __attribute__((ext_vector_type(4))) short short4v;
typedef __attribute__((ext_vector_type(2))) short short2v;
typedef __attribute__((ext_vector_type(4))) float f32x4;
typedef __attribute__((ext_vector_type(2))) _Float16 half2v;
typedef __attribute__((ext_vector_type(4))) _Float16 half4v;
typedef __attribute__((ext_vector_type(8))) _Float16 half8v;

// fp32 -> bf16 (RNE); values here are finite (no NaN handling needed)
__device__ __forceinline__ short f2bf(float f) {
    unsigned u = __float_as_uint(f);
    u += 0x7fff + ((u >> 16) & 1);
    return (short)(u >> 16);
}
__device__ __forceinline__ float bf2f(short h) {
    return __uint_as_float(((unsigned)(unsigned short)h) << 16);
}

// ---------------- CSR build (direct slot scatter -> scan -> in-bin sort+rowptr) ----------
// Node space concatenated: [NP(isa) | NG(rel) | NP(rev)].

__global__ __launch_bounds__(256) void bin_scatter_kernel(
    const int* __restrict__ e0, int E0, const int* __restrict__ e1, int E1,
    const int* __restrict__ e2, int E2, int* __restrict__ bin_cur,
    int* __restrict__ temp, int NPn, int NGn, int nbins, int E_tot) {
    __shared__ int hist[MAXBINS];
    __shared__ int cur[MAXBINS];
    int t = threadIdx.x;
    for (int i = t; i < nbins; i += 256) hist[i] = 0;
    __syncthreads();
    int vals[EPT], bins[EPT];
    int base_e = blockIdx.x * KEDGE;
#pragma unroll
    for (int j = 0; j < EPT; ++j) {
        int g = base_e + j * 256 + t;      // coalesced within each j-step
        int b = -1, v = 0;
        if (g < E_tot) {
            const int* ed; int E, lo, nbase;
            if (g < E0) { ed = e0; E = E0; lo = g; nbase = 0; }
            else if (g < E0 + E1) { ed = e1; E = E1; lo = g - E0; nbase = NPn; }
            else { ed = e2; E = E2; lo = g - E0 - E1; nbase = NPn + NGn; }
            int src = ed[lo];
            int gdst = nbase + ed[E + lo];
            v = src | ((gdst & (BINW - 1)) << 16);
            b = gdst >> BSH;
            atomicAdd(&hist[b], 1);        // LDS atomic
        }
        vals[j] = v;
        bins[j] = b;
    }
    __syncthreads();
    for (int i = t; i < nbins; i += 256) {
        int h = hist[i];
        cur[i] = h ? atomicAdd(&bin_cur[i * 16], h) : 0;   // reserve run (local slot base)
    }
    __syncthreads();
#pragma unroll
    for (int j = 0; j < EPT; ++j) {
        if (bins[j] >= 0) {
            int p = atomicAdd(&cur[bins[j]], 1);           // LDS atomic -> local slot
            if (p < BSLOT) temp[(size_t)bins[j] * BSLOT + p] = vals[j];
        }
    }
}

__global__ __launch_bounds__(1024) void scan_bins(const int* __restrict__ bin_cur, int nbins,
                                                  int* __restrict__ bin_base) {
    __shared__ int sh[1024];
    int t = threadIdx.x;
    int v = 0;
    if (t < nbins) { v = bin_cur[t * 16]; if (v > BSLOT) v = BSLOT; }
    sh[t] = v;
    __syncthreads();
    for (int off = 1; off < 1024; off <<= 1) {
        int u = (t >= off) ? sh[t - off] : 0;
        __syncthreads();
        sh[t] += u;
        __syncthreads();
    }
    if (t < nbins) bin_base[t] = sh[t] - v;    // exclusive
    if (t == nbins - 1) bin_base[nbins] = sh[t];
}

__global__ __launch_bounds__(256) void bin_sort_kernel(
    const int* __restrict__ bin_base, const int* __restrict__ temp,
    int* __restrict__ col, int* __restrict__ rowptr, int n_tot, int nbins) {
    __shared__ int srt[BCAP];
    __shared__ int cur[BINW];
    __shared__ int pfx[BINW];
    __shared__ int red[256];
    int b = blockIdx.x;
    int start = b << BSH;
    int nodes = n_tot - start; if (nodes > BINW) nodes = BINW;
    int t = threadIdx.x;
    int base = bin_base[b];
    int count = bin_base[b + 1] - base;
    const int* __restrict__ tb = temp + (size_t)b * BSLOT;
    for (int i = t; i < BINW; i += 256) cur[i] = 0;
    __syncthreads();
    for (int i = t; i < count; i += 256)
        atomicAdd(&cur[(tb[i] >> 16) & (BINW - 1)], 1);
    __syncthreads();
    int a0 = cur[2 * t], a1 = cur[2 * t + 1];
    red[t] = a0 + a1;
    __syncthreads();
    for (int off = 1; off < 256; off <<= 1) {
        int u = (t >= off) ? red[t - off] : 0;
        __syncthreads();
        red[t] += u;
        __syncthreads();
    }
    int excl = red[t] - (a0 + a1);
    pfx[2 * t] = excl;
    pfx[2 * t + 1] = excl + a0;
    __syncthreads();
    for (int i = t; i < nodes; i += 256) rowptr[start + i] = base + pfx[i];
    if (b == nbins - 1 && t == 0) rowptr[n_tot] = base + count;
    for (int i = t; i < BINW; i += 256) cur[i] = pfx[i];
    __syncthreads();
    if (count <= BCAP) {
        for (int i = t; i < count; i += 256) {
            int v = tb[i];
            int p = atomicAdd(&cur[(v >> 16) & (BINW - 1)], 1);
            srt[p] = v & 0xFFFF;
        }
        __syncthreads();
        for (int i = t; i < count; i += 256) col[base + i] = srt[i];
    } else {  // fallback (not expected): direct global scatter
        for (int i = t; i < count; i += 256) {
            int v = tb[i];
            int p = atomicAdd(&cur[(v >> 16) & (BINW - 1)], 1);
            col[base + p] = v & 0xFFFF;
        }
    }
}

// ---------------- W pack: fp32 [k][n] -> MFMA B-fragment order, split bf16 hi/lo ----------------

struct WSrc { const float* a[15]; const float* b[15]; };

__global__ __launch_bounds__(256) void pack_w_kernel(WSrc src, short* __restrict__ whi,
                                                     short* __restrict__ wlo) {
    int idx = blockIdx.x * 256 + threadIdx.x;   // (mat, kc, ct, lane)
    if (idx >= 15 * 4 * 8 * 64) return;
    int lane = idx & 63;
    int ct = (idx >> 6) & 7;
    int kc = (idx >> 9) & 3;
    int mat = idx >> 11;
    const float* A = src.a[mat];
    const float* Bp = src.b[mat];
    int n = ct * 16 + (lane & 15);
    int kbase = kc * 32 + (lane >> 4) * 8;
    size_t o = (size_t)idx * 8;
    for (int j = 0; j < 8; ++j) {
        float v = A[(size_t)(kbase + j) * H + n];
        if (Bp) v += Bp[(size_t)(kbase + j) * H + n];
        short h = f2bf(v);
        whi[o + j] = h;
        wlo[o + j] = f2bf(v - bf2f(h));
    }
}

// ---------------- fp32 -> fp16 mirror convert (layer-0 inputs, both matrices) ----------------

__global__ __launch_bounds__(256) void cvt16_kernel(const float* __restrict__ xa, int n4a,
                                                    const float* __restrict__ xb, int n4b,
                                                    _Float16* __restrict__ ya,
                                                    _Float16* __restrict__ yb) {
    int i = blockIdx.x * 256 + threadIdx.x;
    const float* x; _Float16* y;
    if (i < n4a) { x = xa + (size_t)i * 4; y = ya + (size_t)i * 4; }
    else if (i < n4a + n4b) { x = xb + (size_t)(i - n4a) * 4; y = yb + (size_t)(i - n4a) * 4; }
    else return;
    f32x4 v = *(const f32x4*)x;
    half4v h;
#pragma unroll
    for (int k = 0; k < 4; ++k) h[k] = (_Float16)v[k];
    *(half4v*)y = h;
}

// ---------------- scalar-base fp16 segment mean (R5-proven codegen; FALLBACK path) ----------

__device__ __forceinline__ float2 seg16(const _Float16* __restrict__ x,
                                        const int* __restrict__ rowptr,
                                        const int* __restrict__ col,
                                        int rb, int voff) {
    int beg = rowptr[rb], end = rowptr[rb + 1];
    float ax0 = 0.f, ax1 = 0.f, ax2 = 0.f, ax3 = 0.f;
    float ay0 = 0.f, ay1 = 0.f, ay2 = 0.f, ay3 = 0.f;
    int e = beg;
    while (e + 16 <= end) {               // uniform loop control
        half2v v[16];
#pragma unroll
        for (int i = 0; i < 16; ++i) {
            int si = __builtin_amdgcn_readfirstlane(col[e + i]);   // SGPR row index
            v[i] = *(const half2v*)(x + (size_t)si * H + voff);    // saddr + voffset
        }
#pragma unroll
        for (int i = 0; i < 16; i += 4) {
            ax0 += (float)v[i + 0][0]; ay0 += (float)v[i + 0][1];
            ax1 += (float)v[i + 1][0]; ay1 += (float)v[i + 1][1];
            ax2 += (float)v[i + 2][0]; ay2 += (float)v[i + 2][1];
            ax3 += (float)v[i + 3][0]; ay3 += (float)v[i + 3][1];
        }
        e += 16;
    }
    int rem = end - e;
    if (rem > 8) {
        int last = end - 1;
        half2v v[16];
#pragma unroll
        for (int i = 0; i < 16; ++i) {
            int p = e + i; if (p > last) p = last;
            int si = __builtin_amdgcn_readfirstlane(col[p]);
            v[i] = *(const half2v*)(x + (size_t)si * H + voff);
        }
#pragma unroll
        for (int i = 0; i < 16; ++i) {
            float m = (i < rem) ? 1.0f : 0.0f;
            float fx = (float)v[i][0], fy = (float)v[i][1];
            if ((i & 3) == 0) { ax0 = fmaf(fx, m, ax0); ay0 = fmaf(fy, m, ay0); }
            else if ((i & 3) == 1) { ax1 = fmaf(fx, m, ax1); ay1 = fmaf(fy, m, ay1); }
            else if ((i & 3) == 2) { ax2 = fmaf(fx, m, ax2); ay2 = fmaf(fy, m, ay2); }
            else { ax3 = fmaf(fx, m, ax3); ay3 = fmaf(fy, m, ay3); }
        }
    } else if (rem > 0) {
        int last = end - 1;
        half2v v[8];
#pragma unroll
        for (int i = 0; i < 8; ++i) {
            int p = e + i; if (p > last) p = last;
            int si = __builtin_amdgcn_readfirstlane(col[p]);
            v[i] = *(const half2v*)(x + (size_t)si * H + voff);
        }
#pragma unroll
        for (int i = 0; i < 8; ++i) {
            float m = (i < rem) ? 1.0f : 0.0f;
            float fx = (float)v[i][0], fy = (float)v[i][1];
            if ((i & 3) == 0) { ax0 = fmaf(fx, m, ax0); ay0 = fmaf(fy, m, ay0); }
            else if ((i & 3) == 1) { ax1 = fmaf(fx, m, ax1); ay1 = fmaf(fy, m, ay1); }
            else if ((i & 3) == 2) { ax2 = fmaf(fx, m, ax2); ay2 = fmaf(fy, m, ay2); }
            else { ax3 = fmaf(fx, m, ax3); ay3 = fmaf(fy, m, ay3); }
        }
    }
    float sx = (ax0 + ax1) + (ax2 + ax3);
    float sy = (ay0 + ay1) + (ay2 + ay3);
    int c = end - beg; if (c < 1) c = 1;
    float inv = 1.0f / (float)c;
    return (float2){sx * inv, sy * inv};
}

// ---------------- fused SAGE layer body ----------------
// Gather terms now use LDS-staged indices (coalesced copy of the block's contiguous col
// range into the dead Alo area) + a branch-free 2-row-interleaved gather: 32 gathers in
// flight per wave, idx round-trip off the critical path. Clamps live on LDS reads (cheap)
// -- NOT on global index loads (the R6/R7 codegen trap). Mean-hi is written to the
// wave's own Ahi rows immediately (other waves only read Alo-idx); lo is kept in regs
// until the post-gather barrier. Math is bit-identical to R5/R8 (same i&3 rotation,
// fmaf(v,1,a) == a+v, same reduce and 1/c multiply).

struct GTerm {
    const _Float16* x;   // gather source mirror (kind: gather if non-null)
    int rbase;           // rowptr base index for this edge type
    const short* hi;     // pre-split planes (kind: copy if non-null)
    const short* lo;
    const float* f;      // fp32 source (layer 0 copy)
};

template <int NIN>
__device__ __forceinline__ void layer_body(
    short* __restrict__ Ahi, short* __restrict__ Alo,
    GTerm t0, GTerm t1, GTerm t2,
    const int* __restrict__ rowptr, const int* __restrict__ col,
    const short* __restrict__ whi, const short* __restrict__ wlo,
    int mat0, int mat1, int mat2,
    const float* __restrict__ b0, const float* __restrict__ b1,
    _Float16* __restrict__ out16, short* __restrict__ ohi, short* __restrict__ olo,
    int n_rows, int relu, int bx) {
    const int tid = threadIdx.x;
    const int lane = tid & 63;
    const int wave = __builtin_amdgcn_readfirstlane(tid >> 6);
    const int r0 = bx * 64;
    const int ct0 = wave * 2;
    const int m16 = lane & 15;
    const int acol = (lane >> 4) * 8;

    f32x4 acc[4][2];
#pragma unroll
    for (int mt = 0; mt < 4; ++mt)
#pragma unroll
        for (int c = 0; c < 2; ++c) acc[mt][c] = (f32x4){0.f, 0.f, 0.f, 0.f};

    const GTerm terms[3] = {t0, t1, t2};
    const int marr[3] = {mat0, mat1, mat2};

#pragma unroll
    for (int m = 0; m < NIN; ++m) {
        const GTerm& T = terms[m];
        __syncthreads();
        if (T.x) {                          // gather-mean term: wave w owns rows 16w..16w+15
            int voff = lane * 2;
            int row_end = r0 + 64; if (row_end > n_rows) row_end = n_rows;
            int beg_blk = rowptr[T.rbase + r0];
            int tcnt = rowptr[T.rbase + row_end] - beg_blk;
            if (tcnt > 0 && tcnt <= IDXCAP) {
                // --- LDS-idx fast path ---
                int* lidx = (int*)Alo;
                for (int i = tid; i < tcnt; i += 256) lidx[i] = col[beg_blk + i];
                __syncthreads();
                short2v lo_sm[16];
#pragma unroll
                for (int pp = 0; pp < 8; ++pp) {
                    int gr0 = r0 + wave * 16 + pp * 2;
                    int gr1 = gr0 + 1;
                    if (gr0 >= n_rows) gr0 = n_rows - 1;   // dup row: harmless recompute
                    if (gr1 >= n_rows) gr1 = n_rows - 1;
                    int rb0 = T.rbase + gr0, rb1 = T.rbase + gr1;
                    int gb0 = rowptr[rb0], ge0 = rowptr[rb0 + 1];
                    int gb1 = rowptr[rb1], ge1 = rowptr[rb1 + 1];
                    int c0 = ge0 - gb0, c1 = ge1 - gb1;
                    int lb0 = gb0 - beg_blk, lb1 = gb1 - beg_blk;
                    int ll0 = (c0 > 0) ? lb0 + c0 - 1 : 0;   // clamp pos (lidx[0] valid)
                    int ll1 = (c1 > 0) ? lb1 + c1 - 1 : 0;
                    int cm = c0 > c1 ? c0 : c1;
                    int mc = (cm + 15) >> 4;
                    float ax0 = 0.f, ax1 = 0.f, ax2 = 0.f, ax3 = 0.f;
                    float ay0 = 0.f, ay1 = 0.f, ay2 = 0.f, ay3 = 0.f;
                    float bx0 = 0.f, bx1 = 0.f, bx2 = 0.f, bx3 = 0.f;
                    float by0 = 0.f, by1 = 0.f, by2 = 0.f, by3 = 0.f;
                    for (int c = 0; c < mc; ++c) {
                        int s0[16], s1[16];
#pragma unroll
                        for (int i = 0; i < 16; ++i) {
                            int q = lb0 + c * 16 + i; if (q > ll0) q = ll0;
                            s0[i] = lidx[q];            // LDS broadcast read
                        }
#pragma unroll
                        for (int i = 0; i < 16; ++i) {
                            int q = lb1 + c * 16 + i; if (q > ll1) q = ll1;
                            s1[i] = lidx[q];
                        }
                        half2v v0[16], v1[16];
#pragma unroll
                        for (int i = 0; i < 16; ++i) {
                            int u = __builtin_amdgcn_readfirstlane(s0[i]);
                            v0[i] = *(const half2v*)(T.x + (size_t)u * H + voff);
                        }
#pragma unroll
                        for (int i = 0; i < 16; ++i) {
                            int u = __builtin_amdgcn_readfirstlane(s1[i]);
                            v1[i] = *(const half2v*)(T.x + (size_t)u * H + voff);
                        }
                        int re0 = c0 - c * 16, re1 = c1 - c * 16;
#pragma unroll
                        for (int i = 0; i < 16; ++i) {
                            float m0 = (i < re0) ? 1.0f : 0.0f;
                            float m1 = (i < re1) ? 1.0f : 0.0f;
                            float fx0 = (float)v0[i][0], fy0 = (float)v0[i][1];
                            float fx1 = (float)v1[i][0], fy1 = (float)v1[i][1];
                            if ((i & 3) == 0) { ax0 = fmaf(fx0, m0, ax0); ay0 = fmaf(fy0, m0, ay0);
                                                bx0 = fmaf(fx1, m1, bx0); by0 = fmaf(fy1, m1, by0); }
                            else if ((i & 3) == 1) { ax1 = fmaf(fx0, m0, ax1); ay1 = fmaf(fy0, m0, ay1);
                                                     bx1 = fmaf(fx1, m1, bx1); by1 = fmaf(fy1, m1, by1); }
                            else if ((i & 3) == 2) { ax2 = fmaf(fx0, m0, ax2); ay2 = fmaf(fy0, m0, ay2);
                                                     bx2 = fmaf(fx1, m1, bx2); by2 = fmaf(fy1, m1, by2); }
                            else { ax3 = fmaf(fx0, m0, ax3); ay3 = fmaf(fy0, m0, ay3);
                                   bx3 = fmaf(fx1, m1, bx3); by3 = fmaf(fy1, m1, by3); }
                        }
                    }
                    int d0 = c0 < 1 ? 1 : c0, d1 = c1 < 1 ? 1 : c1;
                    float i0 = 1.0f / (float)d0, i1 = 1.0f / (float)d1;
                    float sx0 = ((ax0 + ax1) + (ax2 + ax3)) * i0;
                    float sy0 = ((ay0 + ay1) + (ay2 + ay3)) * i0;
                    float sx1 = ((bx0 + bx1) + (bx2 + bx3)) * i1;
                    float sy1 = ((by0 + by1) + (by2 + by3)) * i1;
                    // hi -> own Ahi rows now (Ahi not aliased by idx); lo -> regs
                    int lr0 = wave * 16 + pp * 2;
                    short h00 = f2bf(sx0), h01 = f2bf(sy0);
                    short h10 = f2bf(sx1), h11 = f2bf(sy1);
                    *(short2v*)&Ahi[lr0 * RS + voff] = (short2v){h00, h01};
                    *(short2v*)&Ahi[(lr0 + 1) * RS + voff] = (short2v){h10, h11};
                    lo_sm[pp * 2] = (short2v){f2bf(sx0 - bf2f(h00)), f2bf(sy0 - bf2f(h01))};
                    lo_sm[pp * 2 + 1] = (short2v){f2bf(sx1 - bf2f(h10)), f2bf(sy1 - bf2f(h11))};
                }
                __syncthreads();            // all waves done reading lidx (Alo)
#pragma unroll
                for (int rr = 0; rr < 16; ++rr) {
                    int lrow = wave * 16 + rr;
                    *(short2v*)&Alo[lrow * RS + voff] = lo_sm[rr];
                }
            } else {
                // --- fallback: proven per-row global-idx path (rare / empty block) ---
                for (int rr = 0; rr < 16; ++rr) {
                    int lrow = wave * 16 + rr;
                    int gr = r0 + lrow;
                    if (gr >= n_rows) gr = n_rows - 1;
                    float2 s = seg16(T.x, rowptr, col, T.rbase + gr, voff);
                    short h0 = f2bf(s.x), h1 = f2bf(s.y);
                    *(short2v*)&Ahi[lrow * RS + voff] = (short2v){h0, h1};
                    *(short2v*)&Alo[lrow * RS + voff] =
                        (short2v){f2bf(s.x - bf2f(h0)), f2bf(s.y - bf2f(h1))};
                }
            }
        } else if (T.hi) {                  // pre-split planes: pure copy
#pragma unroll
            for (int i = 0; i < 8; ++i) {
                int f = tid + i * 256;
                int row = f >> 5;
                int c4 = (f & 31) * 4;
                int gr = r0 + row;
                if (gr >= n_rows) gr = n_rows - 1;
                size_t o = (size_t)gr * H + c4;
                *(short4v*)&Ahi[row * RS + c4] = *(const short4v*)&T.hi[o];
                *(short4v*)&Alo[row * RS + c4] = *(const short4v*)&T.lo[o];
            }
        } else {                            // fp32 (layer 0): split on stage
            const float* __restrict__ A = T.f;
#pragma unroll
            for (int i = 0; i < 8; ++i) {
                int f = tid + i * 256;
                int row = f >> 5;
                int c4 = (f & 31) * 4;
                int gr = r0 + row;
                if (gr >= n_rows) gr = n_rows - 1;
                float4 v = *(const float4*)&A[(size_t)gr * H + c4];
                short h0 = f2bf(v.x), h1 = f2bf(v.y), h2 = f2bf(v.z), h3 = f2bf(v.w);
                *(short4v*)&Ahi[row * RS + c4] = (short4v){h0, h1, h2, h3};
                *(short4v*)&Alo[row * RS + c4] =
                    (short4v){f2bf(v.x - bf2f(h0)), f2bf(v.y - bf2f(h1)),
                              f2bf(v.z - bf2f(h2)), f2bf(v.w - bf2f(h3))};
            }
        }
        __syncthreads();
        const short* __restrict__ wh = whi + (size_t)marr[m] * (H * H);
        const short* __restrict__ wl = wlo + (size_t)marr[m] * (H * H);
        short8 bh[2][2], bl[2][2];
        {
            size_t f0 = ((size_t)ct0 * 64 + lane) * 8;
            bh[0][0] = *(const short8*)&wh[f0];
            bh[0][1] = *(const short8*)&wh[f0 + 512];
            bl[0][0] = *(const short8*)&wl[f0];
            bl[0][1] = *(const short8*)&wl[f0 + 512];
        }
#pragma unroll
        for (int kc = 0; kc < 4; ++kc) {
            if (kc < 3) {
                int nb = (kc + 1) & 1;
                size_t f = ((size_t)((kc + 1) * 8 + ct0) * 64 + lane) * 8;
                bh[nb][0] = *(const short8*)&wh[f];
                bh[nb][1] = *(const short8*)&wh[f + 512];
                bl[nb][0] = *(const short8*)&wl[f];
                bl[nb][1] = *(const short8*)&wl[f + 512];
            }
            int cb = kc & 1;
#pragma unroll
            for (int mt = 0; mt < 4; ++mt) {
                short8 ah = *(const short8*)&Ahi[(mt * 16 + m16) * RS + kc * 32 + acol];
                short8 al = *(const short8*)&Alo[(mt * 16 + m16) * RS + kc * 32 + acol];
#pragma unroll
                for (int c = 0; c < 2; ++c) {
                    acc[mt][c] = __builtin_amdgcn_mfma_f32_16x16x32_bf16(ah, bh[cb][c], acc[mt][c], 0, 0, 0);
                    acc[mt][c] = __builtin_amdgcn_mfma_f32_16x16x32_bf16(al, bh[cb][c], acc[mt][c], 0, 0, 0);
                    acc[mt][c] = __builtin_amdgcn_mfma_f32_16x16x32_bf16(ah, bl[cb][c], acc[mt][c], 0, 0, 0);
                }
            }
        }
    }

    const int rquad = (lane >> 4) * 4;
    const int ncol = lane & 15;
#pragma unroll
    for (int c = 0; c < 2; ++c) {
        int n = (ct0 + c) * 16 + ncol;
        float bs = b0[n];
        if (b1) bs += b1[n];
#pragma unroll
        for (int mt = 0; mt < 4; ++mt) {
#pragma unroll
            for (int reg = 0; reg < 4; ++reg) {
                int gr = r0 + mt * 16 + rquad + reg;
                if (gr < n_rows) {
                    float v = acc[mt][c][reg] + bs;
                    if (relu) v = v > 0.f ? v : 0.01f * v;
                    size_t o = (size_t)gr * H + n;
                    out16[o] = (_Float16)v;
                    short h = f2bf(v);
                    ohi[o] = h;
                    olo[o] = f2bf(v - bf2f(h));
                }
            }
        }
    }
}

// One launch per layer: blocks [0, nbp) run the pheno path (3 terms), blocks [nbp, ...)
// run the gene path (2 terms).
struct LayerArgs {
    GTerm p0, p1, p2, g0, g1;
    const int* rowptr; const int* col;
    const short* whi; const short* wlo;
    int pm0, pm1, pm2, gm0, gm1;
    const float* pb0; const float* pb1; const float* gb0;
    _Float16* pout16; short* poh; short* pol; int np;
    _Float16* gout16; short* goh; short* gol; int ng;
    int relu; int nbp;
};

__global__ __launch_bounds__(256, 3) void fused_layer(LayerArgs a) {
    __shared__ short Ahi[64 * RS];
    __shared__ short Alo[64 * RS];
    int bx = blockIdx.x;
    if (bx < a.nbp) {
        layer_body<3>(Ahi, Alo, a.p0, a.p1, a.p2, a.rowptr, a.col, a.whi, a.wlo,
                      a.pm0, a.pm1, a.pm2, a.pb0, a.pb1,
                      a.pout16, a.poh, a.pol, a.np, a.relu, bx);
    } else {
        layer_body<2>(Ahi, Alo, a.g0, a.g1, a.g1, a.rowptr, a.col, a.whi, a.wlo,
                      a.gm0, a.gm1, 0, a.gb0, nullptr,
                      a.gout16, a.goh, a.gol, a.ng, a.relu, bx - a.nbp);
    }
}

// ---------------- edge decoder: sigmoid(dot(xp[i], xg[j])) on fp16 mirrors ----------------

__global__ __launch_bounds__(256) void scores_kernel(const _Float16* __restrict__ xp,
                                                     const _Float16* __restrict__ xg,
                                                     const int* __restrict__ eli, int E,
                                                     float* __restrict__ out) {
    int lane16 = threadIdx.x & 15;
    int sub = threadIdx.x >> 4;     // 16 edges per block
    int e = blockIdx.x * 16 + sub;
    if (e >= E) return;
    int ip = eli[e];
    int ig = eli[E + e];
    half8v a = *(const half8v*)&xp[(size_t)ip * H + lane16 * 8];
    half8v b = *(const half8v*)&xg[(size_t)ig * H + lane16 * 8];
    float s = 0.f;
#pragma unroll
    for (int k = 0; k < 8; ++k) s += (float)a[k] * (float)b[k];
#pragma unroll
    for (int off = 8; off; off >>= 1) s += __shfl_xor(s, off, 16);
    if (lane16 == 0) out[e] = 1.0f / (1.0f + expf(-s));
}

// ---------------- host ----------------

extern "C" void kernel_launch(void* const* d_in, const int* in_sizes, int n_in,
                              void* d_out, int out_size, void* d_ws, size_t ws_size,
                              hipStream_t stream) {
    const float* x_pheno = (const float*)d_in[0];
    const float* x_gene  = (const float*)d_in[1];
    const float* Wl_isa  = (const float*)d_in[2];
    const float* bl_isa  = (const float*)d_in[3];
    const float* Wr_isa  = (const float*)d_in[4];
    const float* Wl_rel  = (const float*)d_in[5];
    const float* bl_rel  = (const float*)d_in[6];
    const float* Wr_rel  = (const float*)d_in[7];
    const float* Wl_rev  = (const float*)d_in[8];
    const float* bl_rev  = (const float*)d_in[9];
    const float* Wr_rev  = (const float*)d_in[10];
    const int* e_isa = (const int*)d_in[11];
    const int* e_rel = (const int*)d_in[12];
    const int* e_rev = (const int*)d_in[13];
    const int* e_lbl = (const int*)d_in[14];
    const int E_isa = in_sizes[11] / 2;
    const int E_rel = in_sizes[12] / 2;
    const int E_rev = in_sizes[13] / 2;
    const int E_lbl = in_sizes[14] / 2;
    const int NP = in_sizes[0] / H;
    const int NG = in_sizes[1] / H;
    const int n_tot = NP + NG + NP;
    const int E_tot = E_isa + E_rel + E_rev;
    const int nbins = (n_tot + BINW - 1) / BINW;

    char* ws = (char*)d_ws;
    auto alloc = [&](size_t bytes) -> char* {
        char* p = ws;
        ws += (bytes + 255) & ~(size_t)255;
        return p;
    };
    int* rowptr  = (int*)alloc((size_t)(n_tot + 1) * 4);
    int* col     = (int*)alloc((size_t)E_tot * 4);
    int* temp    = (int*)alloc((size_t)nbins * BSLOT * 4);
    int* bin_cur = (int*)alloc((size_t)nbins * 16 * 4);   // 64B-strided counters
    int* bin_base= (int*)alloc((size_t)(nbins + 1) * 4);
    short* whi = (short*)alloc((size_t)15 * H * H * sizeof(short));
    short* wlo = (short*)alloc((size_t)15 * H * H * sizeof(short));
    _Float16* xpm[2], *xgm[2];
    xpm[0] = (_Float16*)alloc((size_t)NP * H * sizeof(_Float16));
    xpm[1] = (_Float16*)alloc((size_t)NP * H * sizeof(_Float16));
    xgm[0] = (_Float16*)alloc((size_t)NG * H * sizeof(_Float16));
    xgm[1] = (_Float16*)alloc((size_t)NG * H * sizeof(_Float16));
    short* xph = (short*)alloc((size_t)NP * H * sizeof(short));
    short* xpl = (short*)alloc((size_t)NP * H * sizeof(short));
    short* xgh = (short*)alloc((size_t)NG * H * sizeof(short));
    short* xgl = (short*)alloc((size_t)NG * H * sizeof(short));

    // ---- CSR build (every call; ws is re-poisoned by the harness) ----
    hipMemsetAsync(bin_cur, 0, (size_t)nbins * 16 * 4, stream);
    bin_scatter_kernel<<<(E_tot + KEDGE - 1) / KEDGE, 256, 0, stream>>>(
        e_isa, E_isa, e_rel, E_rel, e_rev, E_rev, bin_cur, temp, NP, NG, nbins, E_tot);
    scan_bins<<<1, 1024, 0, stream>>>(bin_cur, nbins, bin_base);
    bin_sort_kernel<<<nbins, 256, 0, stream>>>(bin_base, temp, col, rowptr, n_tot, nbins);

    // ---- W pack: per layer slots {Wl_isa, Wl_rev, Wsum=Wr_isa+Wr_rev, Wl_rel, Wr_rel} ----
    WSrc src;
    for (int l = 0; l < 3; ++l) {
        src.a[l * 5 + 0] = Wl_isa + (size_t)l * H * H;  src.b[l * 5 + 0] = nullptr;
        src.a[l * 5 + 1] = Wl_rev + (size_t)l * H * H;  src.b[l * 5 + 1] = nullptr;
        src.a[l * 5 + 2] = Wr_isa + (size_t)l * H * H;  src.b[l * 5 + 2] = Wr_rev + (size_t)l * H * H;
        src.a[l * 5 + 3] = Wl_rel + (size_t)l * H * H;  src.b[l * 5 + 3] = nullptr;
        src.a[l * 5 + 4] = Wr_rel + (size_t)l * H * H;  src.b[l * 5 + 4] = nullptr;
    }
    pack_w_kernel<<<(15 * 4 * 8 * 64 + 255) / 256, 256, 0, stream>>>(src, whi, wlo);

    // ---- layer-0 fp16 mirrors of the inputs (set 0) ----
    cvt16_kernel<<<((NP + NG) * 32 + 255) / 256, 256, 0, stream>>>(
        x_pheno, NP * 32, x_gene, NG * 32, xpm[0], xgm[0]);

    // ---- 3 fused layers (one launch each; p blocks lead, g blocks backfill) ----
    const short *pph = nullptr, *ppl = nullptr, *pgh = nullptr, *pgl = nullptr;
    const int nbp = (NP + 63) / 64, nbg = (NG + 63) / 64;
    for (int l = 0; l < 3; ++l) {
        int rs = l & 1;
        int wsid = rs ^ 1;
        LayerArgs a;
        a.p0 = GTerm{xpm[rs], 0, nullptr, nullptr, nullptr};
        a.p1 = GTerm{xgm[rs], NP + NG, nullptr, nullptr, nullptr};
        a.p2 = GTerm{nullptr, 0, pph, ppl, l == 0 ? x_pheno : nullptr};
        a.g0 = GTerm{xpm[rs], NP, nullptr, nullptr, nullptr};
        a.g1 = GTerm{nullptr, 0, pgh, pgl, l == 0 ? x_gene : nullptr};
        a.rowptr = rowptr; a.col = col; a.whi = whi; a.wlo = wlo;
        a.pm0 = l * 5 + 0; a.pm1 = l * 5 + 1; a.pm2 = l * 5 + 2;
        a.gm0 = l * 5 + 3; a.gm1 = l * 5 + 4;
        a.pb0 = bl_isa + (size_t)l * H; a.pb1 = bl_rev + (size_t)l * H;
        a.gb0 = bl_rel + (size_t)l * H;
        a.pout16 = xpm[wsid]; a.poh = xph; a.pol = xpl; a.np = NP;
        a.gout16 = xgm[wsid]; a.goh = xgh; a.gol = xgl; a.ng = NG;
        a.relu = (l < 2) ? 1 : 0; a.nbp = nbp;
        fused_layer<<<nbp + nbg, 256, 0, stream>>>(a);
        pph = xph; ppl = xpl; pgh = xgh; pgl = xgl;
    }

    // ---- decoder (layer 2 wrote mirror set 1) ----
    scores_kernel<<<(E_lbl + 15) / 16, 256, 0, stream>>>(xpm[1], xgm[1], e_lbl, E_lbl,
                                                         (float*)d_out);
}

// Round 10
// 607.159 us; speedup vs baseline: 1.3188x; 1.3188x over previous
//
#include <hip/hip_runtime.h>
#include <hip/hip_bf16.h>
#include <math.h>

#define H 128
#define RS 136    // LDS row stride in shorts (128 + 8 pad; keeps ds_read_b128 16B-aligned)
#define BSH 9     // bin shift: 512 nodes per bin
#define BINW 512
#define BCAP 11264  // max edges/bin for LDS sort
#define BSLOT 12288 // per-bin slot capacity in temp (direct scatter)
#define KEDGE 4096  // edges per partition block
#define EPT 16      // edges per thread (KEDGE/256)
#define MAXBINS 1024

typedef __attribute__((ext_vector_type(8))) short short8;
typedef __attribute__((ext_vector_type(4))) short short4v;
typedef __attribute__((ext_vector_type(2))) short short2v;
typedef __attribute__((ext_vector_type(4))) float f32x4;
typedef __attribute__((ext_vector_type(2))) _Float16 half2v;
typedef __attribute__((ext_vector_type(4))) _Float16 half4v;
typedef __attribute__((ext_vector_type(8))) _Float16 half8v;

// fp32 -> bf16 (RNE); values here are finite (no NaN handling needed)
__device__ __forceinline__ short f2bf(float f) {
    unsigned u = __float_as_uint(f);
    u += 0x7fff + ((u >> 16) & 1);
    return (short)(u >> 16);
}
__device__ __forceinline__ float bf2f(short h) {
    return __uint_as_float(((unsigned)(unsigned short)h) << 16);
}

// ---------------- CSR build (direct slot scatter -> scan -> in-bin sort+rowptr) ----------
// Node space concatenated: [NP(isa) | NG(rel) | NP(rev)].

__global__ __launch_bounds__(256) void bin_scatter_kernel(
    const int* __restrict__ e0, int E0, const int* __restrict__ e1, int E1,
    const int* __restrict__ e2, int E2, int* __restrict__ bin_cur,
    int* __restrict__ temp, int NPn, int NGn, int nbins, int E_tot) {
    __shared__ int hist[MAXBINS];
    __shared__ int cur[MAXBINS];
    int t = threadIdx.x;
    for (int i = t; i < nbins; i += 256) hist[i] = 0;
    __syncthreads();
    int vals[EPT], bins[EPT];
    int base_e = blockIdx.x * KEDGE;
#pragma unroll
    for (int j = 0; j < EPT; ++j) {
        int g = base_e + j * 256 + t;      // coalesced within each j-step
        int b = -1, v = 0;
        if (g < E_tot) {
            const int* ed; int E, lo, nbase;
            if (g < E0) { ed = e0; E = E0; lo = g; nbase = 0; }
            else if (g < E0 + E1) { ed = e1; E = E1; lo = g - E0; nbase = NPn; }
            else { ed = e2; E = E2; lo = g - E0 - E1; nbase = NPn + NGn; }
            int src = ed[lo];
            int gdst = nbase + ed[E + lo];
            v = src | ((gdst & (BINW - 1)) << 16);
            b = gdst >> BSH;
            atomicAdd(&hist[b], 1);        // LDS atomic
        }
        vals[j] = v;
        bins[j] = b;
    }
    __syncthreads();
    for (int i = t; i < nbins; i += 256) {
        int h = hist[i];
        cur[i] = h ? atomicAdd(&bin_cur[i * 16], h) : 0;   // reserve run (local slot base)
    }
    __syncthreads();
#pragma unroll
    for (int j = 0; j < EPT; ++j) {
        if (bins[j] >= 0) {
            int p = atomicAdd(&cur[bins[j]], 1);           // LDS atomic -> local slot
            if (p < BSLOT) temp[(size_t)bins[j] * BSLOT + p] = vals[j];
        }
    }
}

__global__ __launch_bounds__(1024) void scan_bins(const int* __restrict__ bin_cur, int nbins,
                                                  int* __restrict__ bin_base) {
    __shared__ int sh[1024];
    int t = threadIdx.x;
    int v = 0;
    if (t < nbins) { v = bin_cur[t * 16]; if (v > BSLOT) v = BSLOT; }
    sh[t] = v;
    __syncthreads();
    for (int off = 1; off < 1024; off <<= 1) {
        int u = (t >= off) ? sh[t - off] : 0;
        __syncthreads();
        sh[t] += u;
        __syncthreads();
    }
    if (t < nbins) bin_base[t] = sh[t] - v;    // exclusive
    if (t == nbins - 1) bin_base[nbins] = sh[t];
}

__global__ __launch_bounds__(256) void bin_sort_kernel(
    const int* __restrict__ bin_base, const int* __restrict__ temp,
    int* __restrict__ col, int* __restrict__ rowptr, int n_tot, int nbins) {
    __shared__ int srt[BCAP];
    __shared__ int cur[BINW];
    __shared__ int pfx[BINW];
    __shared__ int red[256];
    int b = blockIdx.x;
    int start = b << BSH;
    int nodes = n_tot - start; if (nodes > BINW) nodes = BINW;
    int t = threadIdx.x;
    int base = bin_base[b];
    int count = bin_base[b + 1] - base;
    const int* __restrict__ tb = temp + (size_t)b * BSLOT;
    for (int i = t; i < BINW; i += 256) cur[i] = 0;
    __syncthreads();
    for (int i = t; i < count; i += 256)
        atomicAdd(&cur[(tb[i] >> 16) & (BINW - 1)], 1);
    __syncthreads();
    int a0 = cur[2 * t], a1 = cur[2 * t + 1];
    red[t] = a0 + a1;
    __syncthreads();
    for (int off = 1; off < 256; off <<= 1) {
        int u = (t >= off) ? red[t - off] : 0;
        __syncthreads();
        red[t] += u;
        __syncthreads();
    }
    int excl = red[t] - (a0 + a1);
    pfx[2 * t] = excl;
    pfx[2 * t + 1] = excl + a0;
    __syncthreads();
    for (int i = t; i < nodes; i += 256) rowptr[start + i] = base + pfx[i];
    if (b == nbins - 1 && t == 0) rowptr[n_tot] = base + count;
    for (int i = t; i < BINW; i += 256) cur[i] = pfx[i];
    __syncthreads();
    if (count <= BCAP) {
        for (int i = t; i < count; i += 256) {
            int v = tb[i];
            int p = atomicAdd(&cur[(v >> 16) & (BINW - 1)], 1);
            srt[p] = v & 0xFFFF;
        }
        __syncthreads();
        for (int i = t; i < count; i += 256) col[base + i] = srt[i];
    } else {  // fallback (not expected): direct global scatter
        for (int i = t; i < count; i += 256) {
            int v = tb[i];
            int p = atomicAdd(&cur[(v >> 16) & (BINW - 1)], 1);
            col[base + p] = v & 0xFFFF;
        }
    }
}

// ---------------- W pack: fp32 [k][n] -> MFMA B-fragment order, split bf16 hi/lo ----------------

struct WSrc { const float* a[15]; const float* b[15]; };

__global__ __launch_bounds__(256) void pack_w_kernel(WSrc src, short* __restrict__ whi,
                                                     short* __restrict__ wlo) {
    int idx = blockIdx.x * 256 + threadIdx.x;   // (mat, kc, ct, lane)
    if (idx >= 15 * 4 * 8 * 64) return;
    int lane = idx & 63;
    int ct = (idx >> 6) & 7;
    int kc = (idx >> 9) & 3;
    int mat = idx >> 11;
    const float* A = src.a[mat];
    const float* Bp = src.b[mat];
    int n = ct * 16 + (lane & 15);
    int kbase = kc * 32 + (lane >> 4) * 8;
    size_t o = (size_t)idx * 8;
    for (int j = 0; j < 8; ++j) {
        float v = A[(size_t)(kbase + j) * H + n];
        if (Bp) v += Bp[(size_t)(kbase + j) * H + n];
        short h = f2bf(v);
        whi[o + j] = h;
        wlo[o + j] = f2bf(v - bf2f(h));
    }
}

// ---------------- fp32 -> fp16 mirror convert (layer-0 inputs, both matrices) ----------------

__global__ __launch_bounds__(256) void cvt16_kernel(const float* __restrict__ xa, int n4a,
                                                    const float* __restrict__ xb, int n4b,
                                                    _Float16* __restrict__ ya,
                                                    _Float16* __restrict__ yb) {
    int i = blockIdx.x * 256 + threadIdx.x;
    const float* x; _Float16* y;
    if (i < n4a) { x = xa + (size_t)i * 4; y = ya + (size_t)i * 4; }
    else if (i < n4a + n4b) { x = xb + (size_t)(i - n4a) * 4; y = yb + (size_t)(i - n4a) * 4; }
    else return;
    f32x4 v = *(const f32x4*)x;
    half4v h;
#pragma unroll
    for (int k = 0; k < 4; ++k) h[k] = (_Float16)v[k];
    *(half4v*)y = h;
}

// ---------------- scalar-base fp16 segment mean (R5-proven codegen; DO NOT TOUCH) ----------
// Full chunks: col[e..e+15] contiguous + wave-uniform -> compiler merges to wide s_loads,
// 16 gathers overlapped per chunk. Tails carry the clamps (run once per row).

__device__ __forceinline__ float2 seg16(const _Float16* __restrict__ x,
                                        const int* __restrict__ rowptr,
                                        const int* __restrict__ col,
                                        int rb, int voff) {
    int beg = rowptr[rb], end = rowptr[rb + 1];
    float ax0 = 0.f, ax1 = 0.f, ax2 = 0.f, ax3 = 0.f;
    float ay0 = 0.f, ay1 = 0.f, ay2 = 0.f, ay3 = 0.f;
    int e = beg;
    while (e + 16 <= end) {               // uniform loop control
        half2v v[16];
#pragma unroll
        for (int i = 0; i < 16; ++i) {
            int si = __builtin_amdgcn_readfirstlane(col[e + i]);   // SGPR row index
            v[i] = *(const half2v*)(x + (size_t)si * H + voff);    // saddr + voffset
        }
#pragma unroll
        for (int i = 0; i < 16; i += 4) {
            ax0 += (float)v[i + 0][0]; ay0 += (float)v[i + 0][1];
            ax1 += (float)v[i + 1][0]; ay1 += (float)v[i + 1][1];
            ax2 += (float)v[i + 2][0]; ay2 += (float)v[i + 2][1];
            ax3 += (float)v[i + 3][0]; ay3 += (float)v[i + 3][1];
        }
        e += 16;
    }
    int rem = end - e;
    if (rem > 8) {                        // 9..15 left: one 16-wide masked tail
        int last = end - 1;
        half2v v[16];
#pragma unroll
        for (int i = 0; i < 16; ++i) {
            int p = e + i; if (p > last) p = last;
            int si = __builtin_amdgcn_readfirstlane(col[p]);
            v[i] = *(const half2v*)(x + (size_t)si * H + voff);
        }
#pragma unroll
        for (int i = 0; i < 16; ++i) {
            float m = (i < rem) ? 1.0f : 0.0f;
            float fx = (float)v[i][0], fy = (float)v[i][1];
            if ((i & 3) == 0) { ax0 = fmaf(fx, m, ax0); ay0 = fmaf(fy, m, ay0); }
            else if ((i & 3) == 1) { ax1 = fmaf(fx, m, ax1); ay1 = fmaf(fy, m, ay1); }
            else if ((i & 3) == 2) { ax2 = fmaf(fx, m, ax2); ay2 = fmaf(fy, m, ay2); }
            else { ax3 = fmaf(fx, m, ax3); ay3 = fmaf(fy, m, ay3); }
        }
    } else if (rem > 0) {                 // 1..8 left: one 8-wide masked tail
        int last = end - 1;
        half2v v[8];
#pragma unroll
        for (int i = 0; i < 8; ++i) {
            int p = e + i; if (p > last) p = last;
            int si = __builtin_amdgcn_readfirstlane(col[p]);
            v[i] = *(const half2v*)(x + (size_t)si * H + voff);
        }
#pragma unroll
        for (int i = 0; i < 8; ++i) {
            float m = (i < rem) ? 1.0f : 0.0f;
            float fx = (float)v[i][0], fy = (float)v[i][1];
            if ((i & 3) == 0) { ax0 = fmaf(fx, m, ax0); ay0 = fmaf(fy, m, ay0); }
            else if ((i & 3) == 1) { ax1 = fmaf(fx, m, ax1); ay1 = fmaf(fy, m, ay1); }
            else if ((i & 3) == 2) { ax2 = fmaf(fx, m, ax2); ay2 = fmaf(fy, m, ay2); }
            else { ax3 = fmaf(fx, m, ax3); ay3 = fmaf(fy, m, ay3); }
        }
    }
    float sx = (ax0 + ax1) + (ax2 + ax3);
    float sy = (ay0 + ay1) + (ay2 + ay3);
    int c = end - beg; if (c < 1) c = 1;
    float inv = 1.0f / (float)c;
    return (float2){sx * inv, sy * inv};
}

// ---------------- fused SAGE layer body (R8 structure, verbatim) ----------------

struct GTerm {
    const _Float16* x;   // gather source mirror (kind: gather if non-null)
    int rbase;           // rowptr base index for this edge type
    const short* hi;     // pre-split planes (kind: copy if non-null)
    const short* lo;
    const float* f;      // fp32 source (layer 0 copy)
};

template <int NIN>
__device__ __forceinline__ void layer_body(
    short* __restrict__ Ahi, short* __restrict__ Alo,
    GTerm t0, GTerm t1, GTerm t2,
    const int* __restrict__ rowptr, const int* __restrict__ col,
    const short* __restrict__ whi, const short* __restrict__ wlo,
    int mat0, int mat1, int mat2,
    const float* __restrict__ b0, const float* __restrict__ b1,
    _Float16* __restrict__ out16, short* __restrict__ ohi, short* __restrict__ olo,
    int n_rows, int relu, int bx) {
    const int tid = threadIdx.x;
    const int lane = tid & 63;
    const int wave = __builtin_amdgcn_readfirstlane(tid >> 6);
    const int r0 = bx * 64;
    const int ct0 = wave * 2;
    const int m16 = lane & 15;
    const int acol = (lane >> 4) * 8;

    f32x4 acc[4][2];
#pragma unroll
    for (int mt = 0; mt < 4; ++mt)
#pragma unroll
        for (int c = 0; c < 2; ++c) acc[mt][c] = (f32x4){0.f, 0.f, 0.f, 0.f};

    const GTerm terms[3] = {t0, t1, t2};
    const int marr[3] = {mat0, mat1, mat2};

#pragma unroll
    for (int m = 0; m < NIN; ++m) {
        const GTerm& T = terms[m];
        __syncthreads();
        if (T.x) {                          // gather-mean term: wave w owns rows 16w..16w+15
            int voff = lane * 2;
            for (int rr = 0; rr < 16; ++rr) {
                int lrow = wave * 16 + rr;
                int gr = r0 + lrow;
                if (gr >= n_rows) gr = n_rows - 1;     // dup row: harmless recompute
                float2 s = seg16(T.x, rowptr, col, T.rbase + gr, voff);
                short h0 = f2bf(s.x), h1 = f2bf(s.y);
                *(short2v*)&Ahi[lrow * RS + voff] = (short2v){h0, h1};
                *(short2v*)&Alo[lrow * RS + voff] =
                    (short2v){f2bf(s.x - bf2f(h0)), f2bf(s.y - bf2f(h1))};
            }
        } else if (T.hi) {                  // pre-split planes: pure copy
#pragma unroll
            for (int i = 0; i < 8; ++i) {
                int f = tid + i * 256;
                int row = f >> 5;
                int c4 = (f & 31) * 4;
                int gr = r0 + row;
                if (gr >= n_rows) gr = n_rows - 1;
                size_t o = (size_t)gr * H + c4;
                *(short4v*)&Ahi[row * RS + c4] = *(const short4v*)&T.hi[o];
                *(short4v*)&Alo[row * RS + c4] = *(const short4v*)&T.lo[o];
            }
        } else {                            // fp32 (layer 0): split on stage
            const float* __restrict__ A = T.f;
#pragma unroll
            for (int i = 0; i < 8; ++i) {
                int f = tid + i * 256;
                int row = f >> 5;
                int c4 = (f & 31) * 4;
                int gr = r0 + row;
                if (gr >= n_rows) gr = n_rows - 1;
                float4 v = *(const float4*)&A[(size_t)gr * H + c4];
                short h0 = f2bf(v.x), h1 = f2bf(v.y), h2 = f2bf(v.z), h3 = f2bf(v.w);
                *(short4v*)&Ahi[row * RS + c4] = (short4v){h0, h1, h2, h3};
                *(short4v*)&Alo[row * RS + c4] =
                    (short4v){f2bf(v.x - bf2f(h0)), f2bf(v.y - bf2f(h1)),
                              f2bf(v.z - bf2f(h2)), f2bf(v.w - bf2f(h3))};
            }
        }
        __syncthreads();
        const short* __restrict__ wh = whi + (size_t)marr[m] * (H * H);
        const short* __restrict__ wl = wlo + (size_t)marr[m] * (H * H);
        short8 bh[2][2], bl[2][2];
        {
            size_t f0 = ((size_t)ct0 * 64 + lane) * 8;
            bh[0][0] = *(const short8*)&wh[f0];
            bh[0][1] = *(const short8*)&wh[f0 + 512];
            bl[0][0] = *(const short8*)&wl[f0];
            bl[0][1] = *(const short8*)&wl[f0 + 512];
        }
#pragma unroll
        for (int kc = 0; kc < 4; ++kc) {
            if (kc < 3) {
                int nb = (kc + 1) & 1;
                size_t f = ((size_t)((kc + 1) * 8 + ct0) * 64 + lane) * 8;
                bh[nb][0] = *(const short8*)&wh[f];
                bh[nb][1] = *(const short8*)&wh[f + 512];
                bl[nb][0] = *(const short8*)&wl[f];
                bl[nb][1] = *(const short8*)&wl[f + 512];
            }
            int cb = kc & 1;
#pragma unroll
            for (int mt = 0; mt < 4; ++mt) {
                short8 ah = *(const short8*)&Ahi[(mt * 16 + m16) * RS + kc * 32 + acol];
                short8 al = *(const short8*)&Alo[(mt * 16 + m16) * RS + kc * 32 + acol];
#pragma unroll
                for (int c = 0; c < 2; ++c) {
                    acc[mt][c] = __builtin_amdgcn_mfma_f32_16x16x32_bf16(ah, bh[cb][c], acc[mt][c], 0, 0, 0);
                    acc[mt][c] = __builtin_amdgcn_mfma_f32_16x16x32_bf16(al, bh[cb][c], acc[mt][c], 0, 0, 0);
                    acc[mt][c] = __builtin_amdgcn_mfma_f32_16x16x32_bf16(ah, bl[cb][c], acc[mt][c], 0, 0, 0);
                }
            }
        }
    }

    const int rquad = (lane >> 4) * 4;
    const int ncol = lane & 15;
#pragma unroll
    for (int c = 0; c < 2; ++c) {
        int n = (ct0 + c) * 16 + ncol;
        float bs = b0[n];
        if (b1) bs += b1[n];
#pragma unroll
        for (int mt = 0; mt < 4; ++mt) {
#pragma unroll
            for (int reg = 0; reg < 4; ++reg) {
                int gr = r0 + mt * 16 + rquad + reg;
                if (gr < n_rows) {
                    float v = acc[mt][c][reg] + bs;
                    if (relu) v = v > 0.f ? v : 0.01f * v;
                    size_t o = (size_t)gr * H + n;
                    out16[o] = (_Float16)v;
                    short h = f2bf(v);
                    ohi[o] = h;
                    olo[o] = f2bf(v - bf2f(h));
                }
            }
        }
    }
}

// One launch per layer: blocks [0, nbp) run the pheno path (3 terms), blocks [nbp, ...)
// run the gene path (2 terms). min-waves-per-EU = 4 -> 4 blocks/CU co-resident
// (LDS 34816*4 = 139 KB <= 160 KB; VGPR budget 128 >= the ~60 this kernel needs):
// +33% resident waves on a latency-bound kernel.
struct LayerArgs {
    GTerm p0, p1, p2, g0, g1;
    const int* rowptr; const int* col;
    const short* whi; const short* wlo;
    int pm0, pm1, pm2, gm0, gm1;
    const float* pb0; const float* pb1; const float* gb0;
    _Float16* pout16; short* poh; short* pol; int np;
    _Float16* gout16; short* goh; short* gol; int ng;
    int relu; int nbp;
};

__global__ __launch_bounds__(256, 4) void fused_layer(LayerArgs a) {
    __shared__ short Ahi[64 * RS];
    __shared__ short Alo[64 * RS];
    int bx = blockIdx.x;
    if (bx < a.nbp) {
        layer_body<3>(Ahi, Alo, a.p0, a.p1, a.p2, a.rowptr, a.col, a.whi, a.wlo,
                      a.pm0, a.pm1, a.pm2, a.pb0, a.pb1,
                      a.pout16, a.poh, a.pol, a.np, a.relu, bx);
    } else {
        layer_body<2>(Ahi, Alo, a.g0, a.g1, a.g1, a.rowptr, a.col, a.whi, a.wlo,
                      a.gm0, a.gm1, 0, a.gb0, nullptr,
                      a.gout16, a.goh, a.gol, a.ng, a.relu, bx - a.nbp);
    }
}

// ---------------- edge decoder: sigmoid(dot(xp[i], xg[j])) on fp16 mirrors ----------------

__global__ __launch_bounds__(256) void scores_kernel(const _Float16* __restrict__ xp,
                                                     const _Float16* __restrict__ xg,
                                                     const int* __restrict__ eli, int E,
                                                     float* __restrict__ out) {
    int lane16 = threadIdx.x & 15;
    int sub = threadIdx.x >> 4;     // 16 edges per block
    int e = blockIdx.x * 16 + sub;
    if (e >= E) return;
    int ip = eli[e];
    int ig = eli[E + e];
    half8v a = *(const half8v*)&xp[(size_t)ip * H + lane16 * 8];
    half8v b = *(const half8v*)&xg[(size_t)ig * H + lane16 * 8];
    float s = 0.f;
#pragma unroll
    for (int k = 0; k < 8; ++k) s += (float)a[k] * (float)b[k];
#pragma unroll
    for (int off = 8; off; off >>= 1) s += __shfl_xor(s, off, 16);
    if (lane16 == 0) out[e] = 1.0f / (1.0f + expf(-s));
}

// ---------------- host ----------------

extern "C" void kernel_launch(void* const* d_in, const int* in_sizes, int n_in,
                              void* d_out, int out_size, void* d_ws, size_t ws_size,
                              hipStream_t stream) {
    const float* x_pheno = (const float*)d_in[0];
    const float* x_gene  = (const float*)d_in[1];
    const float* Wl_isa  = (const float*)d_in[2];
    const float* bl_isa  = (const float*)d_in[3];
    const float* Wr_isa  = (const float*)d_in[4];
    const float* Wl_rel  = (const float*)d_in[5];
    const float* bl_rel  = (const float*)d_in[6];
    const float* Wr_rel  = (const float*)d_in[7];
    const float* Wl_rev  = (const float*)d_in[8];
    const float* bl_rev  = (const float*)d_in[9];
    const float* Wr_rev  = (const float*)d_in[10];
    const int* e_isa = (const int*)d_in[11];
    const int* e_rel = (const int*)d_in[12];
    const int* e_rev = (const int*)d_in[13];
    const int* e_lbl = (const int*)d_in[14];
    const int E_isa = in_sizes[11] / 2;
    const int E_rel = in_sizes[12] / 2;
    const int E_rev = in_sizes[13] / 2;
    const int E_lbl = in_sizes[14] / 2;
    const int NP = in_sizes[0] / H;
    const int NG = in_sizes[1] / H;
    const int n_tot = NP + NG + NP;
    const int E_tot = E_isa + E_rel + E_rev;
    const int nbins = (n_tot + BINW - 1) / BINW;

    char* ws = (char*)d_ws;
    auto alloc = [&](size_t bytes) -> char* {
        char* p = ws;
        ws += (bytes + 255) & ~(size_t)255;
        return p;
    };
    int* rowptr  = (int*)alloc((size_t)(n_tot + 1) * 4);
    int* col     = (int*)alloc((size_t)E_tot * 4 + 64);   // +64B slack for future prefetch
    int* temp    = (int*)alloc((size_t)nbins * BSLOT * 4);
    int* bin_cur = (int*)alloc((size_t)nbins * 16 * 4);   // 64B-strided counters
    int* bin_base= (int*)alloc((size_t)(nbins + 1) * 4);
    short* whi = (short*)alloc((size_t)15 * H * H * sizeof(short));
    short* wlo = (short*)alloc((size_t)15 * H * H * sizeof(short));
    _Float16* xpm[2], *xgm[2];
    xpm[0] = (_Float16*)alloc((size_t)NP * H * sizeof(_Float16));
    xpm[1] = (_Float16*)alloc((size_t)NP * H * sizeof(_Float16));
    xgm[0] = (_Float16*)alloc((size_t)NG * H * sizeof(_Float16));
    xgm[1] = (_Float16*)alloc((size_t)NG * H * sizeof(_Float16));
    short* xph = (short*)alloc((size_t)NP * H * sizeof(short));
    short* xpl = (short*)alloc((size_t)NP * H * sizeof(short));
    short* xgh = (short*)alloc((size_t)NG * H * sizeof(short));
    short* xgl = (short*)alloc((size_t)NG * H * sizeof(short));

    // ---- CSR build (every call; ws is re-poisoned by the harness) ----
    hipMemsetAsync(bin_cur, 0, (size_t)nbins * 16 * 4, stream);
    bin_scatter_kernel<<<(E_tot + KEDGE - 1) / KEDGE, 256, 0, stream>>>(
        e_isa, E_isa, e_rel, E_rel, e_rev, E_rev, bin_cur, temp, NP, NG, nbins, E_tot);
    scan_bins<<<1, 1024, 0, stream>>>(bin_cur, nbins, bin_base);
    bin_sort_kernel<<<nbins, 256, 0, stream>>>(bin_base, temp, col, rowptr, n_tot, nbins);

    // ---- W pack: per layer slots {Wl_isa, Wl_rev, Wsum=Wr_isa+Wr_rev, Wl_rel, Wr_rel} ----
    WSrc src;
    for (int l = 0; l < 3; ++l) {
        src.a[l * 5 + 0] = Wl_isa + (size_t)l * H * H;  src.b[l * 5 + 0] = nullptr;
        src.a[l * 5 + 1] = Wl_rev + (size_t)l * H * H;  src.b[l * 5 + 1] = nullptr;
        src.a[l * 5 + 2] = Wr_isa + (size_t)l * H * H;  src.b[l * 5 + 2] = Wr_rev + (size_t)l * H * H;
        src.a[l * 5 + 3] = Wl_rel + (size_t)l * H * H;  src.b[l * 5 + 3] = nullptr;
        src.a[l * 5 + 4] = Wr_rel + (size_t)l * H * H;  src.b[l * 5 + 4] = nullptr;
    }
    pack_w_kernel<<<(15 * 4 * 8 * 64 + 255) / 256, 256, 0, stream>>>(src, whi, wlo);

    // ---- layer-0 fp16 mirrors of the inputs (set 0) ----
    cvt16_kernel<<<((NP + NG) * 32 + 255) / 256, 256, 0, stream>>>(
        x_pheno, NP * 32, x_gene, NG * 32, xpm[0], xgm[0]);

    // ---- 3 fused layers (one launch each; p blocks lead, g blocks backfill) ----
    const short *pph = nullptr, *ppl = nullptr, *pgh = nullptr, *pgl = nullptr;
    const int nbp = (NP + 63) / 64, nbg = (NG + 63) / 64;
    for (int l = 0; l < 3; ++l) {
        int rs = l & 1;
        int wsid = rs ^ 1;
        LayerArgs a;
        a.p0 = GTerm{xpm[rs], 0, nullptr, nullptr, nullptr};
        a.p1 = GTerm{xgm[rs], NP + NG, nullptr, nullptr, nullptr};
        a.p2 = GTerm{nullptr, 0, pph, ppl, l == 0 ? x_pheno : nullptr};
        a.g0 = GTerm{xpm[rs], NP, nullptr, nullptr, nullptr};
        a.g1 = GTerm{nullptr, 0, pgh, pgl, l == 0 ? x_gene : nullptr};
        a.rowptr = rowptr; a.col = col; a.whi = whi; a.wlo = wlo;
        a.pm0 = l * 5 + 0; a.pm1 = l * 5 + 1; a.pm2 = l * 5 + 2;
        a.gm0 = l * 5 + 3; a.gm1 = l * 5 + 4;
        a.pb0 = bl_isa + (size_t)l * H; a.pb1 = bl_rev + (size_t)l * H;
        a.gb0 = bl_rel + (size_t)l * H;
        a.pout16 = xpm[wsid]; a.poh = xph; a.pol = xpl; a.np = NP;
        a.gout16 = xgm[wsid]; a.goh = xgh; a.gol = xgl; a.ng = NG;
        a.relu = (l < 2) ? 1 : 0; a.nbp = nbp;
        fused_layer<<<nbp + nbg, 256, 0, stream>>>(a);
        pph = xph; ppl = xpl; pgh = xgh; pgl = xgl;
    }

    // ---- decoder (layer 2 wrote mirror set 1) ----
    scores_kernel<<<(E_lbl + 15) / 16, 256, 0, stream>>>(xpm[1], xgm[1], e_lbl, E_lbl,
                                                         (float*)d_out);
}

// Round 11
// 599.709 us; speedup vs baseline: 1.3352x; 1.0124x over previous
//
#include <hip/hip_runtime.h>
#include <hip/hip_bf16.h>
#include <math.h>

#define H 128
#define RS 136    // LDS row stride in shorts (128 + 8 pad; keeps ds_read_b128 16B-aligned)
#define BSH 9     // bin shift: 512 nodes per bin
#define BINW 512
#define BCAP 11264  // max edges/bin for LDS sort
#define BSLOT 12288 // per-bin slot capacity in temp (direct scatter)
#define KEDGE 4096  // edges per partition block
#define EPT 16      // edges per thread (KEDGE/256)
#define MAXBINS 1024

typedef __attribute__((ext_vector_type(8))) short short8;
typedef __attribute__((ext_vector_type(4))) short short4v;
typedef __attribute__((ext_vector_type(2))) short short2v;
typedef __attribute__((ext_vector_type(4))) float f32x4;
typedef __attribute__((ext_vector_type(2))) _Float16 half2v;
typedef __attribute__((ext_vector_type(4))) _Float16 half4v;
typedef __attribute__((ext_vector_type(8))) _Float16 half8v;

// fp32 -> bf16 (RNE); values here are finite (no NaN handling needed)
__device__ __forceinline__ short f2bf(float f) {
    unsigned u = __float_as_uint(f);
    u += 0x7fff + ((u >> 16) & 1);
    return (short)(u >> 16);
}
__device__ __forceinline__ float bf2f(short h) {
    return __uint_as_float(((unsigned)(unsigned short)h) << 16);
}

// ---------------- CSR build (direct slot scatter -> scan -> in-bin sort+rowptr) ----------
// Node space concatenated: [NP(isa) | NG(rel) | NP(rev)].

__global__ __launch_bounds__(256) void bin_scatter_kernel(
    const int* __restrict__ e0, int E0, const int* __restrict__ e1, int E1,
    const int* __restrict__ e2, int E2, int* __restrict__ bin_cur,
    int* __restrict__ temp, int NPn, int NGn, int nbins, int E_tot) {
    __shared__ int hist[MAXBINS];
    __shared__ int cur[MAXBINS];
    int t = threadIdx.x;
    for (int i = t; i < nbins; i += 256) hist[i] = 0;
    __syncthreads();
    int vals[EPT], bins[EPT];
    int base_e = blockIdx.x * KEDGE;
#pragma unroll
    for (int j = 0; j < EPT; ++j) {
        int g = base_e + j * 256 + t;      // coalesced within each j-step
        int b = -1, v = 0;
        if (g < E_tot) {
            const int* ed; int E, lo, nbase;
            if (g < E0) { ed = e0; E = E0; lo = g; nbase = 0; }
            else if (g < E0 + E1) { ed = e1; E = E1; lo = g - E0; nbase = NPn; }
            else { ed = e2; E = E2; lo = g - E0 - E1; nbase = NPn + NGn; }
            int src = ed[lo];
            int gdst = nbase + ed[E + lo];
            v = src | ((gdst & (BINW - 1)) << 16);
            b = gdst >> BSH;
            atomicAdd(&hist[b], 1);        // LDS atomic
        }
        vals[j] = v;
        bins[j] = b;
    }
    __syncthreads();
    for (int i = t; i < nbins; i += 256) {
        int h = hist[i];
        cur[i] = h ? atomicAdd(&bin_cur[i * 16], h) : 0;   // reserve run (local slot base)
    }
    __syncthreads();
#pragma unroll
    for (int j = 0; j < EPT; ++j) {
        if (bins[j] >= 0) {
            int p = atomicAdd(&cur[bins[j]], 1);           // LDS atomic -> local slot
            if (p < BSLOT) temp[(size_t)bins[j] * BSLOT + p] = vals[j];
        }
    }
}

__global__ __launch_bounds__(1024) void scan_bins(const int* __restrict__ bin_cur, int nbins,
                                                  int* __restrict__ bin_base) {
    __shared__ int sh[1024];
    int t = threadIdx.x;
    int v = 0;
    if (t < nbins) { v = bin_cur[t * 16]; if (v > BSLOT) v = BSLOT; }
    sh[t] = v;
    __syncthreads();
    for (int off = 1; off < 1024; off <<= 1) {
        int u = (t >= off) ? sh[t - off] : 0;
        __syncthreads();
        sh[t] += u;
        __syncthreads();
    }
    if (t < nbins) bin_base[t] = sh[t] - v;    // exclusive
    if (t == nbins - 1) bin_base[nbins] = sh[t];
}

__global__ __launch_bounds__(256) void bin_sort_kernel(
    const int* __restrict__ bin_base, const int* __restrict__ temp,
    int* __restrict__ col, int* __restrict__ rowptr, int n_tot, int nbins) {
    __shared__ int srt[BCAP];
    __shared__ int cur[BINW];
    __shared__ int pfx[BINW];
    __shared__ int red[256];
    int b = blockIdx.x;
    int start = b << BSH;
    int nodes = n_tot - start; if (nodes > BINW) nodes = BINW;
    int t = threadIdx.x;
    int base = bin_base[b];
    int count = bin_base[b + 1] - base;
    const int* __restrict__ tb = temp + (size_t)b * BSLOT;
    for (int i = t; i < BINW; i += 256) cur[i] = 0;
    __syncthreads();
    for (int i = t; i < count; i += 256)
        atomicAdd(&cur[(tb[i] >> 16) & (BINW - 1)], 1);
    __syncthreads();
    int a0 = cur[2 * t], a1 = cur[2 * t + 1];
    red[t] = a0 + a1;
    __syncthreads();
    for (int off = 1; off < 256; off <<= 1) {
        int u = (t >= off) ? red[t - off] : 0;
        __syncthreads();
        red[t] += u;
        __syncthreads();
    }
    int excl = red[t] - (a0 + a1);
    pfx[2 * t] = excl;
    pfx[2 * t + 1] = excl + a0;
    __syncthreads();
    for (int i = t; i < nodes; i += 256) rowptr[start + i] = base + pfx[i];
    if (b == nbins - 1 && t == 0) rowptr[n_tot] = base + count;
    for (int i = t; i < BINW; i += 256) cur[i] = pfx[i];
    __syncthreads();
    if (count <= BCAP) {
        for (int i = t; i < count; i += 256) {
            int v = tb[i];
            int p = atomicAdd(&cur[(v >> 16) & (BINW - 1)], 1);
            srt[p] = v & 0xFFFF;
        }
        __syncthreads();
        for (int i = t; i < count; i += 256) col[base + i] = srt[i];
    } else {  // fallback (not expected): direct global scatter
        for (int i = t; i < count; i += 256) {
            int v = tb[i];
            int p = atomicAdd(&cur[(v >> 16) & (BINW - 1)], 1);
            col[base + p] = v & 0xFFFF;
        }
    }
}

// ---------------- W pack: fp32 [k][n] -> MFMA B-fragment order, split bf16 hi/lo ----------------

struct WSrc { const float* a[15]; const float* b[15]; };

__global__ __launch_bounds__(256) void pack_w_kernel(WSrc src, short* __restrict__ whi,
                                                     short* __restrict__ wlo) {
    int idx = blockIdx.x * 256 + threadIdx.x;   // (mat, kc, ct, lane)
    if (idx >= 15 * 4 * 8 * 64) return;
    int lane = idx & 63;
    int ct = (idx >> 6) & 7;
    int kc = (idx >> 9) & 3;
    int mat = idx >> 11;
    const float* A = src.a[mat];
    const float* Bp = src.b[mat];
    int n = ct * 16 + (lane & 15);
    int kbase = kc * 32 + (lane >> 4) * 8;
    size_t o = (size_t)idx * 8;
    for (int j = 0; j < 8; ++j) {
        float v = A[(size_t)(kbase + j) * H + n];
        if (Bp) v += Bp[(size_t)(kbase + j) * H + n];
        short h = f2bf(v);
        whi[o + j] = h;
        wlo[o + j] = f2bf(v - bf2f(h));
    }
}

// ---------------- fp32 -> fp16 mirror convert (layer-0 inputs, both matrices) ----------------

__global__ __launch_bounds__(256) void cvt16_kernel(const float* __restrict__ xa, int n4a,
                                                    const float* __restrict__ xb, int n4b,
                                                    _Float16* __restrict__ ya,
                                                    _Float16* __restrict__ yb) {
    int i = blockIdx.x * 256 + threadIdx.x;
    const float* x; _Float16* y;
    if (i < n4a) { x = xa + (size_t)i * 4; y = ya + (size_t)i * 4; }
    else if (i < n4a + n4b) { x = xb + (size_t)(i - n4a) * 4; y = yb + (size_t)(i - n4a) * 4; }
    else return;
    f32x4 v = *(const f32x4*)x;
    half4v h;
#pragma unroll
    for (int k = 0; k < 4; ++k) h[k] = (_Float16)v[k];
    *(half4v*)y = h;
}

// ---------------- scalar-base fp16 segment mean (R5-proven codegen; DO NOT TOUCH) ----------
// Full chunks: col[e..e+15] contiguous + wave-uniform -> compiler merges to wide s_loads,
// 16 gathers overlapped per chunk. Tails carry the clamps (run once per row).

__device__ __forceinline__ float2 seg16(const _Float16* __restrict__ x,
                                        const int* __restrict__ rowptr,
                                        const int* __restrict__ col,
                                        int rb, int voff) {
    int beg = rowptr[rb], end = rowptr[rb + 1];
    float ax0 = 0.f, ax1 = 0.f, ax2 = 0.f, ax3 = 0.f;
    float ay0 = 0.f, ay1 = 0.f, ay2 = 0.f, ay3 = 0.f;
    int e = beg;
    while (e + 16 <= end) {               // uniform loop control
        half2v v[16];
#pragma unroll
        for (int i = 0; i < 16; ++i) {
            int si = __builtin_amdgcn_readfirstlane(col[e + i]);   // SGPR row index
            v[i] = *(const half2v*)(x + (size_t)si * H + voff);    // saddr + voffset
        }
#pragma unroll
        for (int i = 0; i < 16; i += 4) {
            ax0 += (float)v[i + 0][0]; ay0 += (float)v[i + 0][1];
            ax1 += (float)v[i + 1][0]; ay1 += (float)v[i + 1][1];
            ax2 += (float)v[i + 2][0]; ay2 += (float)v[i + 2][1];
            ax3 += (float)v[i + 3][0]; ay3 += (float)v[i + 3][1];
        }
        e += 16;
    }
    int rem = end - e;
    if (rem > 8) {                        // 9..15 left: one 16-wide masked tail
        int last = end - 1;
        half2v v[16];
#pragma unroll
        for (int i = 0; i < 16; ++i) {
            int p = e + i; if (p > last) p = last;
            int si = __builtin_amdgcn_readfirstlane(col[p]);
            v[i] = *(const half2v*)(x + (size_t)si * H + voff);
        }
#pragma unroll
        for (int i = 0; i < 16; ++i) {
            float m = (i < rem) ? 1.0f : 0.0f;
            float fx = (float)v[i][0], fy = (float)v[i][1];
            if ((i & 3) == 0) { ax0 = fmaf(fx, m, ax0); ay0 = fmaf(fy, m, ay0); }
            else if ((i & 3) == 1) { ax1 = fmaf(fx, m, ax1); ay1 = fmaf(fy, m, ay1); }
            else if ((i & 3) == 2) { ax2 = fmaf(fx, m, ax2); ay2 = fmaf(fy, m, ay2); }
            else { ax3 = fmaf(fx, m, ax3); ay3 = fmaf(fy, m, ay3); }
        }
    } else if (rem > 0) {                 // 1..8 left: one 8-wide masked tail
        int last = end - 1;
        half2v v[8];
#pragma unroll
        for (int i = 0; i < 8; ++i) {
            int p = e + i; if (p > last) p = last;
            int si = __builtin_amdgcn_readfirstlane(col[p]);
            v[i] = *(const half2v*)(x + (size_t)si * H + voff);
        }
#pragma unroll
        for (int i = 0; i < 8; ++i) {
            float m = (i < rem) ? 1.0f : 0.0f;
            float fx = (float)v[i][0], fy = (float)v[i][1];
            if ((i & 3) == 0) { ax0 = fmaf(fx, m, ax0); ay0 = fmaf(fy, m, ay0); }
            else if ((i & 3) == 1) { ax1 = fmaf(fx, m, ax1); ay1 = fmaf(fy, m, ay1); }
            else if ((i & 3) == 2) { ax2 = fmaf(fx, m, ax2); ay2 = fmaf(fy, m, ay2); }
            else { ax3 = fmaf(fx, m, ax3); ay3 = fmaf(fy, m, ay3); }
        }
    }
    float sx = (ax0 + ax1) + (ax2 + ax3);
    float sy = (ay0 + ay1) + (ay2 + ay3);
    int c = end - beg; if (c < 1) c = 1;
    float inv = 1.0f / (float)c;
    return (float2){sx * inv, sy * inv};
}

// ---------------- fused SAGE layer body: 8-wave (512-thread) blocks over 64-row tiles -----
// Gather: wave w owns rows 8w..8w+7 per term (half R8's serial chain depth per wave; 2x
// resident gather waves -> 2x outstanding gathers per CU). MFMA: each wave owns ONE
// 16-col tile (ct0 = wave), acc[4], single B-fragment double-buffer -- same fragment
// layout, same kc order, same triple-MFMA split as the proven 4-wave form; arithmetic
// per output element is bit-identical (only the wave->output mapping changed).

struct GTerm {
    const _Float16* x;   // gather source mirror (kind: gather if non-null)
    int rbase;           // rowptr base index for this edge type
    const short* hi;     // pre-split planes (kind: copy if non-null)
    const short* lo;
    const float* f;      // fp32 source (layer 0 copy)
};

template <int NIN>
__device__ __forceinline__ void layer_body(
    short* __restrict__ Ahi, short* __restrict__ Alo,
    GTerm t0, GTerm t1, GTerm t2,
    const int* __restrict__ rowptr, const int* __restrict__ col,
    const short* __restrict__ whi, const short* __restrict__ wlo,
    int mat0, int mat1, int mat2,
    const float* __restrict__ b0, const float* __restrict__ b1,
    _Float16* __restrict__ out16, short* __restrict__ ohi, short* __restrict__ olo,
    int n_rows, int relu, int bx) {
    const int tid = threadIdx.x;
    const int lane = tid & 63;
    const int wave = __builtin_amdgcn_readfirstlane(tid >> 6);   // 0..7
    const int r0 = bx * 64;
    const int ct0 = wave;              // one 16-col tile per wave
    const int m16 = lane & 15;
    const int acol = (lane >> 4) * 8;

    f32x4 acc[4];
#pragma unroll
    for (int mt = 0; mt < 4; ++mt) acc[mt] = (f32x4){0.f, 0.f, 0.f, 0.f};

    const GTerm terms[3] = {t0, t1, t2};
    const int marr[3] = {mat0, mat1, mat2};

#pragma unroll
    for (int m = 0; m < NIN; ++m) {
        const GTerm& T = terms[m];
        __syncthreads();
        if (T.x) {                          // gather-mean term: wave w owns rows 8w..8w+7
            int voff = lane * 2;
            for (int rr = 0; rr < 8; ++rr) {
                int lrow = wave * 8 + rr;
                int gr = r0 + lrow;
                if (gr >= n_rows) gr = n_rows - 1;     // dup row: harmless recompute
                float2 s = seg16(T.x, rowptr, col, T.rbase + gr, voff);
                short h0 = f2bf(s.x), h1 = f2bf(s.y);
                *(short2v*)&Ahi[lrow * RS + voff] = (short2v){h0, h1};
                *(short2v*)&Alo[lrow * RS + voff] =
                    (short2v){f2bf(s.x - bf2f(h0)), f2bf(s.y - bf2f(h1))};
            }
        } else if (T.hi) {                  // pre-split planes: pure copy
#pragma unroll
            for (int i = 0; i < 4; ++i) {
                int f = tid + i * 512;
                int row = f >> 5;
                int c4 = (f & 31) * 4;
                int gr = r0 + row;
                if (gr >= n_rows) gr = n_rows - 1;
                size_t o = (size_t)gr * H + c4;
                *(short4v*)&Ahi[row * RS + c4] = *(const short4v*)&T.hi[o];
                *(short4v*)&Alo[row * RS + c4] = *(const short4v*)&T.lo[o];
            }
        } else {                            // fp32 (layer 0): split on stage
            const float* __restrict__ A = T.f;
#pragma unroll
            for (int i = 0; i < 4; ++i) {
                int f = tid + i * 512;
                int row = f >> 5;
                int c4 = (f & 31) * 4;
                int gr = r0 + row;
                if (gr >= n_rows) gr = n_rows - 1;
                float4 v = *(const float4*)&A[(size_t)gr * H + c4];
                short h0 = f2bf(v.x), h1 = f2bf(v.y), h2 = f2bf(v.z), h3 = f2bf(v.w);
                *(short4v*)&Ahi[row * RS + c4] = (short4v){h0, h1, h2, h3};
                *(short4v*)&Alo[row * RS + c4] =
                    (short4v){f2bf(v.x - bf2f(h0)), f2bf(v.y - bf2f(h1)),
                              f2bf(v.z - bf2f(h2)), f2bf(v.w - bf2f(h3))};
            }
        }
        __syncthreads();
        const short* __restrict__ wh = whi + (size_t)marr[m] * (H * H);
        const short* __restrict__ wl = wlo + (size_t)marr[m] * (H * H);
        short8 bh[2], bl[2];
        {
            size_t f0 = ((size_t)ct0 * 64 + lane) * 8;
            bh[0] = *(const short8*)&wh[f0];
            bl[0] = *(const short8*)&wl[f0];
        }
#pragma unroll
        for (int kc = 0; kc < 4; ++kc) {
            if (kc < 3) {
                int nb = (kc + 1) & 1;
                size_t f = ((size_t)((kc + 1) * 8 + ct0) * 64 + lane) * 8;
                bh[nb] = *(const short8*)&wh[f];
                bl[nb] = *(const short8*)&wl[f];
            }
            int cb = kc & 1;
#pragma unroll
            for (int mt = 0; mt < 4; ++mt) {
                short8 ah = *(const short8*)&Ahi[(mt * 16 + m16) * RS + kc * 32 + acol];
                short8 al = *(const short8*)&Alo[(mt * 16 + m16) * RS + kc * 32 + acol];
                acc[mt] = __builtin_amdgcn_mfma_f32_16x16x32_bf16(ah, bh[cb], acc[mt], 0, 0, 0);
                acc[mt] = __builtin_amdgcn_mfma_f32_16x16x32_bf16(al, bh[cb], acc[mt], 0, 0, 0);
                acc[mt] = __builtin_amdgcn_mfma_f32_16x16x32_bf16(ah, bl[cb], acc[mt], 0, 0, 0);
            }
        }
    }

    const int rquad = (lane >> 4) * 4;
    const int ncol = lane & 15;
    {
        int n = ct0 * 16 + ncol;
        float bs = b0[n];
        if (b1) bs += b1[n];
#pragma unroll
        for (int mt = 0; mt < 4; ++mt) {
#pragma unroll
            for (int reg = 0; reg < 4; ++reg) {
                int gr = r0 + mt * 16 + rquad + reg;
                if (gr < n_rows) {
                    float v = acc[mt][reg] + bs;
                    if (relu) v = v > 0.f ? v : 0.01f * v;
                    size_t o = (size_t)gr * H + n;
                    out16[o] = (_Float16)v;
                    short h = f2bf(v);
                    ohi[o] = h;
                    olo[o] = f2bf(v - bf2f(h));
                }
            }
        }
    }
}

// One launch per layer: blocks [0, nbp) run the pheno path (3 terms), blocks [nbp, ...)
// run the gene path (2 terms). 512 threads (8 waves) per block; LDS 34.8 KB -> 4
// blocks/CU = 32 waves/CU (max occupancy) when VGPR <= 64.
struct LayerArgs {
    GTerm p0, p1, p2, g0, g1;
    const int* rowptr; const int* col;
    const short* whi; const short* wlo;
    int pm0, pm1, pm2, gm0, gm1;
    const float* pb0; const float* pb1; const float* gb0;
    _Float16* pout16; short* poh; short* pol; int np;
    _Float16* gout16; short* goh; short* gol; int ng;
    int relu; int nbp;
};

__global__ __launch_bounds__(512, 4) void fused_layer(LayerArgs a) {
    __shared__ short Ahi[64 * RS];
    __shared__ short Alo[64 * RS];
    int bx = blockIdx.x;
    if (bx < a.nbp) {
        layer_body<3>(Ahi, Alo, a.p0, a.p1, a.p2, a.rowptr, a.col, a.whi, a.wlo,
                      a.pm0, a.pm1, a.pm2, a.pb0, a.pb1,
                      a.pout16, a.poh, a.pol, a.np, a.relu, bx);
    } else {
        layer_body<2>(Ahi, Alo, a.g0, a.g1, a.g1, a.rowptr, a.col, a.whi, a.wlo,
                      a.gm0, a.gm1, 0, a.gb0, nullptr,
                      a.gout16, a.goh, a.gol, a.ng, a.relu, bx - a.nbp);
    }
}

// ---------------- edge decoder: sigmoid(dot(xp[i], xg[j])) on fp16 mirrors ----------------

__global__ __launch_bounds__(256) void scores_kernel(const _Float16* __restrict__ xp,
                                                     const _Float16* __restrict__ xg,
                                                     const int* __restrict__ eli, int E,
                                                     float* __restrict__ out) {
    int lane16 = threadIdx.x & 15;
    int sub = threadIdx.x >> 4;     // 16 edges per block
    int e = blockIdx.x * 16 + sub;
    if (e >= E) return;
    int ip = eli[e];
    int ig = eli[E + e];
    half8v a = *(const half8v*)&xp[(size_t)ip * H + lane16 * 8];
    half8v b = *(const half8v*)&xg[(size_t)ig * H + lane16 * 8];
    float s = 0.f;
#pragma unroll
    for (int k = 0; k < 8; ++k) s += (float)a[k] * (float)b[k];
#pragma unroll
    for (int off = 8; off; off >>= 1) s += __shfl_xor(s, off, 16);
    if (lane16 == 0) out[e] = 1.0f / (1.0f + expf(-s));
}

// ---------------- host ----------------

extern "C" void kernel_launch(void* const* d_in, const int* in_sizes, int n_in,
                              void* d_out, int out_size, void* d_ws, size_t ws_size,
                              hipStream_t stream) {
    const float* x_pheno = (const float*)d_in[0];
    const float* x_gene  = (const float*)d_in[1];
    const float* Wl_isa  = (const float*)d_in[2];
    const float* bl_isa  = (const float*)d_in[3];
    const float* Wr_isa  = (const float*)d_in[4];
    const float* Wl_rel  = (const float*)d_in[5];
    const float* bl_rel  = (const float*)d_in[6];
    const float* Wr_rel  = (const float*)d_in[7];
    const float* Wl_rev  = (const float*)d_in[8];
    const float* bl_rev  = (const float*)d_in[9];
    const float* Wr_rev  = (const float*)d_in[10];
    const int* e_isa = (const int*)d_in[11];
    const int* e_rel = (const int*)d_in[12];
    const int* e_rev = (const int*)d_in[13];
    const int* e_lbl = (const int*)d_in[14];
    const int E_isa = in_sizes[11] / 2;
    const int E_rel = in_sizes[12] / 2;
    const int E_rev = in_sizes[13] / 2;
    const int E_lbl = in_sizes[14] / 2;
    const int NP = in_sizes[0] / H;
    const int NG = in_sizes[1] / H;
    const int n_tot = NP + NG + NP;
    const int E_tot = E_isa + E_rel + E_rev;
    const int nbins = (n_tot + BINW - 1) / BINW;

    char* ws = (char*)d_ws;
    auto alloc = [&](size_t bytes) -> char* {
        char* p = ws;
        ws += (bytes + 255) & ~(size_t)255;
        return p;
    };
    int* rowptr  = (int*)alloc((size_t)(n_tot + 1) * 4);
    int* col     = (int*)alloc((size_t)E_tot * 4 + 64);   // +64B slack
    int* temp    = (int*)alloc((size_t)nbins * BSLOT * 4);
    int* bin_cur = (int*)alloc((size_t)nbins * 16 * 4);   // 64B-strided counters
    int* bin_base= (int*)alloc((size_t)(nbins + 1) * 4);
    short* whi = (short*)alloc((size_t)15 * H * H * sizeof(short));
    short* wlo = (short*)alloc((size_t)15 * H * H * sizeof(short));
    _Float16* xpm[2], *xgm[2];
    xpm[0] = (_Float16*)alloc((size_t)NP * H * sizeof(_Float16));
    xpm[1] = (_Float16*)alloc((size_t)NP * H * sizeof(_Float16));
    xgm[0] = (_Float16*)alloc((size_t)NG * H * sizeof(_Float16));
    xgm[1] = (_Float16*)alloc((size_t)NG * H * sizeof(_Float16));
    short* xph = (short*)alloc((size_t)NP * H * sizeof(short));
    short* xpl = (short*)alloc((size_t)NP * H * sizeof(short));
    short* xgh = (short*)alloc((size_t)NG * H * sizeof(short));
    short* xgl = (short*)alloc((size_t)NG * H * sizeof(short));

    // ---- CSR build (every call; ws is re-poisoned by the harness) ----
    hipMemsetAsync(bin_cur, 0, (size_t)nbins * 16 * 4, stream);
    bin_scatter_kernel<<<(E_tot + KEDGE - 1) / KEDGE, 256, 0, stream>>>(
        e_isa, E_isa, e_rel, E_rel, e_rev, E_rev, bin_cur, temp, NP, NG, nbins, E_tot);
    scan_bins<<<1, 1024, 0, stream>>>(bin_cur, nbins, bin_base);
    bin_sort_kernel<<<nbins, 256, 0, stream>>>(bin_base, temp, col, rowptr, n_tot, nbins);

    // ---- W pack: per layer slots {Wl_isa, Wl_rev, Wsum=Wr_isa+Wr_rev, Wl_rel, Wr_rel} ----
    WSrc src;
    for (int l = 0; l < 3; ++l) {
        src.a[l * 5 + 0] = Wl_isa + (size_t)l * H * H;  src.b[l * 5 + 0] = nullptr;
        src.a[l * 5 + 1] = Wl_rev + (size_t)l * H * H;  src.b[l * 5 + 1] = nullptr;
        src.a[l * 5 + 2] = Wr_isa + (size_t)l * H * H;  src.b[l * 5 + 2] = Wr_rev + (size_t)l * H * H;
        src.a[l * 5 + 3] = Wl_rel + (size_t)l * H * H;  src.b[l * 5 + 3] = nullptr;
        src.a[l * 5 + 4] = Wr_rel + (size_t)l * H * H;  src.b[l * 5 + 4] = nullptr;
    }
    pack_w_kernel<<<(15 * 4 * 8 * 64 + 255) / 256, 256, 0, stream>>>(src, whi, wlo);

    // ---- layer-0 fp16 mirrors of the inputs (set 0) ----
    cvt16_kernel<<<((NP + NG) * 32 + 255) / 256, 256, 0, stream>>>(
        x_pheno, NP * 32, x_gene, NG * 32, xpm[0], xgm[0]);

    // ---- 3 fused layers (one launch each; p blocks lead, g blocks backfill) ----
    const short *pph = nullptr, *ppl = nullptr, *pgh = nullptr, *pgl = nullptr;
    const int nbp = (NP + 63) / 64, nbg = (NG + 63) / 64;
    for (int l = 0; l < 3; ++l) {
        int rs = l & 1;
        int wsid = rs ^ 1;
        LayerArgs a;
        a.p0 = GTerm{xpm[rs], 0, nullptr, nullptr, nullptr};
        a.p1 = GTerm{xgm[rs], NP + NG, nullptr, nullptr, nullptr};
        a.p2 = GTerm{nullptr, 0, pph, ppl, l == 0 ? x_pheno : nullptr};
        a.g0 = GTerm{xpm[rs], NP, nullptr, nullptr, nullptr};
        a.g1 = GTerm{nullptr, 0, pgh, pgl, l == 0 ? x_gene : nullptr};
        a.rowptr = rowptr; a.col = col; a.whi = whi; a.wlo = wlo;
        a.pm0 = l * 5 + 0; a.pm1 = l * 5 + 1; a.pm2 = l * 5 + 2;
        a.gm0 = l * 5 + 3; a.gm1 = l * 5 + 4;
        a.pb0 = bl_isa + (size_t)l * H; a.pb1 = bl_rev + (size_t)l * H;
        a.gb0 = bl_rel + (size_t)l * H;
        a.pout16 = xpm[wsid]; a.poh = xph; a.pol = xpl; a.np = NP;
        a.gout16 = xgm[wsid]; a.goh = xgh; a.gol = xgl; a.ng = NG;
        a.relu = (l < 2) ? 1 : 0; a.nbp = nbp;
        fused_layer<<<nbp + nbg, 512, 0, stream>>>(a);
        pph = xph; ppl = xpl; pgh = xgh; pgl = xgl;
    }

    // ---- decoder (layer 2 wrote mirror set 1) ----
    scores_kernel<<<(E_lbl + 15) / 16, 256, 0, stream>>>(xpm[1], xgm[1], e_lbl, E_lbl,
                                                         (float*)d_out);
}